// Round 10
// baseline (237.002 us; speedup 1.0000x reference)
//
#include <hip/hip_runtime.h>
#include <math.h>

#define B_ 16
#define N_ 288
#define C_ 32
#define H_ 32
#define BN_ (B_ * N_)       // 4608
#define NT 4                // nodes per wave in kernel 1
#define K1GRID (BN_ / NT)   // 1152

#define TI4 4
#define NTILES4 (N_ / TI4)  // 72
#define K2TGRID (B_ * NTILES4)  // 1152
#define TI6 6
#define NTILES6 (N_ / TI6)  // 48
#define K2SGRID (B_ * NTILES6)  // 768

typedef float v2f __attribute__((ext_vector_type(2)));

// ---------------------------------------------------------------------------
// ATTRIBUTION VIA GRID REPLICATION. Each kernel maps bx % base -> work item;
// production launches use grid == base (identity); probe launches use
// grid = base * REP, blocks re-write byte-identical values (benign races).
// True production codegen, true occupancy shape, no rep-loop distortion.
// ---------------------------------------------------------------------------

// K1: round-2-exact GRU structure (NT=4, one wave/block), now writing ps/pr
// row-major AND prT transposed (both pair variants consumable).
__global__ __launch_bounds__(64) void gru_proj_kernel(
    const float* __restrict__ inputs, const float* __restrict__ states,
    const float* __restrict__ rzW,    const float* __restrict__ rzb,
    const float* __restrict__ hcW,    const float* __restrict__ hcb,
    const float* __restrict__ c1W,    const float* __restrict__ c1b,
    const float* __restrict__ c2W,    const float* __restrict__ c2b,
    float* __restrict__ out_state,
    float* __restrict__ ps1, float* __restrict__ pr1,
    float* __restrict__ ps2, float* __restrict__ pr2,
    float* __restrict__ pr1T, float* __restrict__ pr2T)
{
    const int lane  = threadIdx.x;
    const int o     = lane & 31;
    const int half  = lane >> 5;
    const int node0 = (blockIdx.x % K1GRID) * NT;

    __shared__ float rs_sh[NT][32];
    __shared__ float a_sh[NT][32];

    // ---- r_z = sigmoid(x @ rzW + rzb); lane = out unit (64) ----
    float acc[NT];
    const float rzbias = rzb[lane];
    #pragma unroll
    for (int t = 0; t < NT; ++t) acc[t] = rzbias;

    #pragma unroll
    for (int k = 0; k < C_; ++k) {
        const float wk = rzW[k * 64 + lane];
        #pragma unroll
        for (int t = 0; t < NT; ++t)
            acc[t] = fmaf(inputs[(node0 + t) * C_ + k], wk, acc[t]);
    }
    #pragma unroll
    for (int k = 0; k < H_; ++k) {
        const float wk = rzW[(C_ + k) * 64 + lane];
        #pragma unroll
        for (int t = 0; t < NT; ++t)
            acc[t] = fmaf(states[(node0 + t) * H_ + k], wk, acc[t]);
    }

    float z[NT], st[NT];
    #pragma unroll
    for (int t = 0; t < NT; ++t) {
        const float rzv = 1.0f / (1.0f + __expf(-acc[t]));
        const float r   = __shfl(rzv, o);
        z[t]  = __shfl(rzv, o + 32);
        st[t] = states[(node0 + t) * H_ + o];
        if (lane < 32) rs_sh[t][o] = r * st[t];
    }
    __syncthreads();

    // ---- h_cand = tanh(concat(x, r*state) @ hcW + hcb) ----
    float acc2[NT];
    #pragma unroll
    for (int t = 0; t < NT; ++t) acc2[t] = 0.0f;

    #pragma unroll
    for (int k = 0; k < C_; ++k) {
        const float wk = hcW[k * H_ + o];
        #pragma unroll
        for (int t = 0; t < NT; ++t)
            acc2[t] = fmaf(inputs[(node0 + t) * C_ + k], wk, acc2[t]);
    }
    #pragma unroll
    for (int q = 0; q < 8; ++q) {
        float4 rq[NT];
        #pragma unroll
        for (int t = 0; t < NT; ++t)
            rq[t] = *(const float4*)&rs_sh[t][q * 4];
        #pragma unroll
        for (int k4 = 0; k4 < 4; ++k4) {
            const float wk = hcW[(C_ + q * 4 + k4) * H_ + o];
            #pragma unroll
            for (int t = 0; t < NT; ++t)
                acc2[t] = fmaf(((const float*)&rq[t])[k4], wk, acc2[t]);
        }
    }

    const float hcbias = hcb[o];
    #pragma unroll
    for (int t = 0; t < NT; ++t) {
        const float e  = __expf(2.0f * (acc2[t] + hcbias));
        const float hc = 1.0f - 2.0f / (e + 1.0f);   // tanh
        const float ns = z[t] * st[t] + (1.0f - z[t]) * hc;
        if (lane < 32) out_state[(node0 + t) * H_ + o] = ns;
        const float av = fmaxf(ns, 0.0f);
        if (lane < 32) a_sh[t][o] = av;
    }
    __syncthreads();

    // ---- projections: lane = [sender unit | receiver unit] ----
    const int rb = half * 32;
    float p1[NT], p2[NT];
    const float b1v = c1b[o], b2v = c2b[o];
    #pragma unroll
    for (int t = 0; t < NT; ++t) {
        p1[t] = half ? 0.0f : b1v;       // fc2 bias folded into sender
        p2[t] = half ? 0.0f : b2v;
    }
    #pragma unroll
    for (int q = 0; q < 8; ++q) {
        float4 aq[NT];
        #pragma unroll
        for (int t = 0; t < NT; ++t)
            aq[t] = *(const float4*)&a_sh[t][q * 4];
        #pragma unroll
        for (int k4 = 0; k4 < 4; ++k4) {
            const int h    = q * 4 + k4;
            const float w1 = c1W[(rb + h) * H_ + o];
            const float w2 = c2W[(rb + h) * H_ + o];
            #pragma unroll
            for (int t = 0; t < NT; ++t) {
                const float av = ((const float*)&aq[t])[k4];
                p1[t] = fmaf(av, w1, p1[t]);
                p2[t] = fmaf(av, w2, p2[t]);
            }
        }
    }
    if (!half) {
        #pragma unroll
        for (int t = 0; t < NT; ++t) {
            ps1[(node0 + t) * H_ + o] = p1[t];
            ps2[(node0 + t) * H_ + o] = p2[t];
        }
    } else {
        const int qo = o >> 2, ro = o & 3;
        #pragma unroll
        for (int t = 0; t < NT; ++t) {
            pr1[(node0 + t) * H_ + o] = p1[t];
            pr2[(node0 + t) * H_ + o] = p2[t];
            pr1T[((size_t)qo * BN_ + node0 + t) * 4 + ro] = p1[t];
            pr2T[((size_t)qo * BN_ + node0 + t) * 4 + ro] = p2[t];
        }
    }
}

// K2 variant T: LDS-staged ps, transposed coalesced prT, packed-f32.
__global__ __launch_bounds__(320) void pair_T_kernel(
    const float* __restrict__ ps1, const float* __restrict__ pr1T,
    const float* __restrict__ ps2, const float* __restrict__ pr2T,
    const float* __restrict__ w1g, const float* __restrict__ b1g,
    const float* __restrict__ w2g, const float* __restrict__ b2g,
    float* __restrict__ out)
{
    const int tid = threadIdx.x;
    const int bxm = blockIdx.x % K2TGRID;
    const int b   = bxm / NTILES4;
    const int i0  = (bxm % NTILES4) * TI4;

    __shared__ __align__(16) float s1[TI4 * 32];
    __shared__ __align__(16) float s2[TI4 * 32];

    const size_t rowbase = (size_t)(b * N_ + i0) * H_;
    if (tid < TI4 * 32)            s1[tid]            = ps1[rowbase + tid];
    else if (tid < 2 * TI4 * 32)   s2[tid - TI4 * 32] = ps2[rowbase + (tid - TI4 * 32)];
    __syncthreads();

    const int j = tid;
    if (j < N_) {
        const size_t jj = (size_t)(b * N_ + j);
        const v2f zero = {0.0f, 0.0f};
        float acc1[TI4];
        {
            const float4* prp = (const float4*)pr1T;
            v2f p0[8], p1v[8], w0[8], w1v[8];
            #pragma unroll
            for (int c = 0; c < 8; ++c) {
                const float4 pv = prp[(size_t)c * BN_ + jj];   // coalesced
                p0[c]  = (v2f){pv.x, pv.y};
                p1v[c] = (v2f){pv.z, pv.w};
                w0[c]  = (v2f){w1g[4 * c + 0], w1g[4 * c + 1]};
                w1v[c] = (v2f){w1g[4 * c + 2], w1g[4 * c + 3]};
            }
            const float b1 = b1g[0];
            #pragma unroll
            for (int ii = 0; ii < TI4; ++ii) {
                v2f aA = {b1, 0.0f}, aB = zero;
                #pragma unroll
                for (int c = 0; c < 8; ++c) {
                    const float4 sv = *(const float4*)&s1[ii * 32 + c * 4];
                    v2f u0 = (v2f){sv.x, sv.y} + p0[c];
                    v2f u1 = (v2f){sv.z, sv.w} + p1v[c];
                    u0 = __builtin_elementwise_max(u0, zero);
                    u1 = __builtin_elementwise_max(u1, zero);
                    aA = u0 * w0[c] + aA;
                    aB = u1 * w1v[c] + aB;
                }
                acc1[ii] = aA.x + aA.y + aB.x + aB.y;
            }
        }
        {
            const float4* prp = (const float4*)pr2T;
            v2f p0[8], p1v[8], w0[8], w1v[8];
            #pragma unroll
            for (int c = 0; c < 8; ++c) {
                const float4 pv = prp[(size_t)c * BN_ + jj];
                p0[c]  = (v2f){pv.x, pv.y};
                p1v[c] = (v2f){pv.z, pv.w};
                w0[c]  = (v2f){w2g[4 * c + 0], w2g[4 * c + 1]};
                w1v[c] = (v2f){w2g[4 * c + 2], w2g[4 * c + 3]};
            }
            const float b2 = b2g[0];
            float* orow = out + (size_t)(b * N_ + i0) * N_ + j;
            #pragma unroll
            for (int ii = 0; ii < TI4; ++ii) {
                v2f aA = {b2, 0.0f}, aB = zero;
                #pragma unroll
                for (int c = 0; c < 8; ++c) {
                    const float4 sv = *(const float4*)&s2[ii * 32 + c * 4];
                    v2f u0 = (v2f){sv.x, sv.y} + p0[c];
                    v2f u1 = (v2f){sv.z, sv.w} + p1v[c];
                    u0 = __builtin_elementwise_max(u0, zero);
                    u1 = __builtin_elementwise_max(u1, zero);
                    aA = u0 * w0[c] + aA;
                    aB = u1 * w1v[c] + aB;
                }
                const float m   = aA.x + aA.y + aB.x + aB.y;
                const float sig = 1.0f / (1.0f + __expf(-m));
                orow[(size_t)ii * N_] = acc1[ii] * sig;
            }
        }
    }
}

// K2 variant S: round-2-exact (TI=6, ps+pr row-major, uniform s_loads).
__global__ __launch_bounds__(320) void pair_smem_kernel(
    const float* __restrict__ ps1, const float* __restrict__ pr1,
    const float* __restrict__ ps2, const float* __restrict__ pr2,
    const float* __restrict__ w1g, const float* __restrict__ b1g,
    const float* __restrict__ w2g, const float* __restrict__ b2g,
    float* __restrict__ out)
{
    const int j   = threadIdx.x;
    const int bxm = blockIdx.x % K2SGRID;
    const int b   = bxm / NTILES6;
    const int i0  = (bxm % NTILES6) * TI6;
    if (j >= N_) return;

    const size_t rowbase = (size_t)(b * N_ + i0) * H_;
    float acc1[TI6];
    float4 p[8];
    float  wv[32];
    {
        const float4* prp = (const float4*)(pr1 + (size_t)(b * N_ + j) * H_);
        #pragma unroll
        for (int c = 0; c < 8; ++c) p[c] = prp[c];
        #pragma unroll
        for (int h = 0; h < 32; ++h) wv[h] = w1g[h];
        const float b1 = b1g[0];
        #pragma unroll
        for (int ii = 0; ii < TI6; ++ii) {
            const float4* sp = (const float4*)(ps1 + rowbase + (size_t)ii * H_);
            float aA = b1, aB = 0.0f;
            #pragma unroll
            for (int c = 0; c < 8; ++c) {
                const float4 sv = sp[c];
                const float t0 = fmaxf(sv.x + p[c].x, 0.0f);
                const float t1 = fmaxf(sv.y + p[c].y, 0.0f);
                const float t2 = fmaxf(sv.z + p[c].z, 0.0f);
                const float t3 = fmaxf(sv.w + p[c].w, 0.0f);
                aA = fmaf(t0, wv[4 * c + 0], aA);
                aB = fmaf(t1, wv[4 * c + 1], aB);
                aA = fmaf(t2, wv[4 * c + 2], aA);
                aB = fmaf(t3, wv[4 * c + 3], aB);
            }
            acc1[ii] = aA + aB;
        }
    }
    {
        const float4* prp = (const float4*)(pr2 + (size_t)(b * N_ + j) * H_);
        #pragma unroll
        for (int c = 0; c < 8; ++c) p[c] = prp[c];
        #pragma unroll
        for (int h = 0; h < 32; ++h) wv[h] = w2g[h];
        const float b2 = b2g[0];
        float* orow = out + (size_t)(b * N_ + i0) * N_ + j;
        #pragma unroll
        for (int ii = 0; ii < TI6; ++ii) {
            const float4* sp = (const float4*)(ps2 + rowbase + (size_t)ii * H_);
            float aA = b2, aB = 0.0f;
            #pragma unroll
            for (int c = 0; c < 8; ++c) {
                const float4 sv = sp[c];
                const float t0 = fmaxf(sv.x + p[c].x, 0.0f);
                const float t1 = fmaxf(sv.y + p[c].y, 0.0f);
                const float t2 = fmaxf(sv.z + p[c].z, 0.0f);
                const float t3 = fmaxf(sv.w + p[c].w, 0.0f);
                aA = fmaf(t0, wv[4 * c + 0], aA);
                aB = fmaf(t1, wv[4 * c + 1], aB);
                aA = fmaf(t2, wv[4 * c + 2], aA);
                aB = fmaf(t3, wv[4 * c + 3], aB);
            }
            const float m   = aA + aB;
            const float sig = 1.0f / (1.0f + __expf(-m));
            orow[(size_t)ii * N_] = acc1[ii] * sig;
        }
    }
}

extern "C" void kernel_launch(void* const* d_in, const int* in_sizes, int n_in,
                              void* d_out, int out_size, void* d_ws, size_t ws_size,
                              hipStream_t stream) {
    const float* inputs = (const float*)d_in[0];
    const float* states = (const float*)d_in[1];
    const float* rzW    = (const float*)d_in[2];
    const float* rzb    = (const float*)d_in[3];
    const float* hcW    = (const float*)d_in[4];
    const float* hcb    = (const float*)d_in[5];
    const float* c1W    = (const float*)d_in[6];
    const float* c1b    = (const float*)d_in[7];
    const float* c1w1   = (const float*)d_in[8];
    const float* c1b1   = (const float*)d_in[9];
    const float* c2W    = (const float*)d_in[10];
    const float* c2b    = (const float*)d_in[11];
    const float* c2w1   = (const float*)d_in[12];
    const float* c2b1   = (const float*)d_in[13];

    float* out_support = (float*)d_out;
    float* out_state   = out_support + (size_t)BN_ * N_;

    float* ws   = (float*)d_ws;
    float* ps1  = ws;
    float* pr1  = ws + 1 * (size_t)BN_ * H_;
    float* ps2  = ws + 2 * (size_t)BN_ * H_;
    float* pr2  = ws + 3 * (size_t)BN_ * H_;
    float* pr1T = ws + 4 * (size_t)BN_ * H_;
    float* pr2T = ws + 5 * (size_t)BN_ * H_;

    // ---- production ----
    gru_proj_kernel<<<K1GRID, 64, 0, stream>>>(
        inputs, states, rzW, rzb, hcW, hcb, c1W, c1b, c2W, c2b,
        out_state, ps1, pr1, ps2, pr2, pr1T, pr2T);
    pair_T_kernel<<<K2TGRID, 320, 0, stream>>>(
        ps1, pr1T, ps2, pr2T, c1w1, c1b1, c2w1, c2b1, out_support);

    // ---- probes (grid replication; byte-identical rewrites) ----
    gru_proj_kernel<<<K1GRID * 24, 64, 0, stream>>>(
        inputs, states, rzW, rzb, hcW, hcb, c1W, c1b, c2W, c2b,
        out_state, ps1, pr1, ps2, pr2, pr1T, pr2T);
    pair_T_kernel<<<K2TGRID * 12, 320, 0, stream>>>(
        ps1, pr1T, ps2, pr2T, c1w1, c1b1, c2w1, c2b1, out_support);
    pair_smem_kernel<<<K2SGRID * 12, 320, 0, stream>>>(
        ps1, pr1, ps2, pr2, c1w1, c1b1, c2w1, c2b1, out_support);
}